// Round 15
// baseline (178.010 us; speedup 1.0000x reference)
//
#include <hip/hip_runtime.h>
#include <hip/hip_bf16.h>
#include <math.h>

typedef float v2f __attribute__((ext_vector_type(2)));
typedef float v4f __attribute__((ext_vector_type(4)));
typedef float f32x8 __attribute__((ext_vector_type(8)));

// Problem constants
#define NQ1 1001      // NQ+1 rows in embed tables
#define KK 5
#define MM 50
#define KD 64
#define VD 64
#define SD 50
#define BB 512
#define SS 500

#define NW 8          // waves per scan block
#define WIN 8         // scan steps per window
#define NWIN 62       // full windows (62*8 = 496; tail = 4 steps = 2 pairs)

// Workspace layout (in floats)
#define OFF_ATTN   0                        // [1001][64] attn rows, cols 50..63 = 0
#define OFF_SQ     (OFF_ATTN + NQ1*64)      // [1001][64] q_embed @ Ws[64:128]
#define OFF_EAD    (OFF_SQ   + NQ1*64)      // [5005][128] interleaved (e,ad) per v
#define OFF_WST    (OFF_EAD  + NQ1*KK*128)  // [50][64] transposed top of Ws
#define OFF_WCT    (OFF_WST  + SD*64)       // [5][50] transposed Wc (pad to 256)
#define OFF_READS  (OFF_WCT  + 256)         // [512*500][64]

#define LGKM_BARRIER() asm volatile("s_waitcnt lgkmcnt(0)\n\ts_barrier" ::: "memory")
#define SCHED_FENCE() __builtin_amdgcn_sched_barrier(0)
#define RL(x_) __builtin_amdgcn_readfirstlane(x_)

// scalar load of one 32B attn slice: dst (8 SGPRs) <- attn_tab + byteoff
#define SLOAD(dst_, off_) \
  asm volatile("s_load_dwordx8 %0, %1, %2" : "=s"(dst_) : "s"(attn_tab), "s"(off_))

// ---------------- kernel 1: all tables (qtab softmax+Sq, transposes, ead) ----------------
__global__ __launch_bounds__(64) void k_tabs(
    const float* __restrict__ qtab, const float* __restrict__ itab,
    const float* __restrict__ keymem,
    const float* __restrict__ Wv, const float* __restrict__ bv,
    const float* __restrict__ We, const float* __restrict__ be,
    const float* __restrict__ Wa, const float* __restrict__ ba,
    const float* __restrict__ Ws, const float* __restrict__ Wc,
    float* __restrict__ attn_tab, float* __restrict__ sq_tab,
    float* __restrict__ ead_tab, float* __restrict__ WsT, float* __restrict__ WcT) {
  const int bid = blockIdx.x;
  const int t = threadIdx.x;

  if (bid < NQ1) {  // ---- per-question: attn softmax row + sq row ----
    const int q = bid;
    __shared__ float qe[64];
    qe[t] = qtab[q * KD + t];
    __syncthreads();

    float dot = 0.f;
    if (t < MM) {
#pragma unroll
      for (int i = 0; i < KD; ++i) dot = fmaf(qe[i], keymem[t * KD + i], dot);
    }
    float xv = (t < MM) ? dot : -1e30f;
#pragma unroll
    for (int off = 32; off; off >>= 1) xv = fmaxf(xv, __shfl_xor(xv, off));
    float p = (t < MM) ? __expf(dot - xv) : 0.f;
    float sum = p;
#pragma unroll
    for (int off = 32; off; off >>= 1) sum += __shfl_xor(sum, off);
    attn_tab[q * 64 + t] = p / sum;   // pad lanes (t>=50) write 0

    float sq = 0.f;
    if (t < SD) {
#pragma unroll
      for (int i = 0; i < KD; ++i) sq = fmaf(qe[i], Ws[(64 + i) * SD + t], sq);
    }
    sq_tab[q * 64 + t] = (t < SD) ? sq : 0.f;
    return;
  }

  if (bid == NQ1) {  // ---- transposes ----
    for (int idx = t; idx < 64 * SD; idx += 64) {
      int i = idx / SD, j = idx % SD;
      WsT[j * 64 + i] = Ws[idx];
    }
    for (int idx = t; idx < SD * KK; idx += 64) {
      int j = idx / KK, c = idx % KK;
      WcT[c * SD + j] = Wc[idx];
    }
    return;
  }

  // ---- per-(q,r) erase/add, interleaved ----
  const int qr = bid - (NQ1 + 1);
  const int q = qr / KK, r = qr % KK;
  const int v = t;
  __shared__ float item[64];
  __shared__ float ves[64];
  item[v] = itab[q * KD + v];
  __syncthreads();

  float ve = bv[v];
#pragma unroll
  for (int i = 0; i < KD; ++i) ve = fmaf(item[i], Wv[i * VD + v], ve);
#pragma unroll
  for (int k = 0; k < KK; ++k) {
    float rf = fmaxf(0.f, 1.f - fabsf((float)k - (float)r) * 0.25f);
    ve = fmaf(rf, Wv[(KD + k) * VD + v], ve);
  }
  ves[v] = ve;
  __syncthreads();

  float se = be[v], sa = ba[v];
#pragma unroll
  for (int i = 0; i < VD; ++i) {
    float x = ves[i];
    se = fmaf(x, We[i * VD + v], se);
    sa = fmaf(x, Wa[i * VD + v], sa);
  }
  float ex = __expf(2.f * sa);
  ead_tab[qr * 128 + 2 * v]     = 1.f / (1.f + __expf(-se));
  ead_tab[qr * 128 + 2 * v + 1] = (ex - 1.f) / (ex + 1.f);
}

// ---------------- kernel 2: scan (R14 + paired LDS payloads, role-split waves) ----------------
__global__ __launch_bounds__(512) void k_scan(
    const int* __restrict__ qs, const int* __restrict__ rs,
    const float* __restrict__ attn_tab, const float* __restrict__ ead_tab,
    const float* __restrict__ init_vm, float* __restrict__ reads) {
  const int b = blockIdx.x;
  const int tid = threadIdx.x;
  const int w = tid >> 6;       // wave id 0..7 (m-slots w*8 .. w*8+7)
  const int v = tid & 63;       // value column
  const int mbase = w * 8;
  const int wb = w << 5;        // byte offset of wave's slice within a row

  __shared__ v2f   red2[2][4][NW][64];      // 32 KB paired read partials
  __shared__ v4f   eadbuf[2][4][64];        // 8 KB (e0,ad0,e1,ad1) per pair
  __shared__ __align__(16) int sidx_a[512]; // 2 KB per-step attn byte offsets

  const int* __restrict__ qb = qs + b * SS;
  const int* __restrict__ rb = rs + b * SS;
  float* __restrict__ outp = reads + (size_t)b * SS * 64;

  // ---- fill per-step attn byte offsets (entries 500..511 clamped) ----
  {
    int idx = (tid < SS) ? tid : (SS - 1);
    sidx_a[tid] = qb[idx] << 8;
  }

  // ---- prologue: waves 4-7 stage window 0 ead pairs; prefetch window-1 q/r ----
  const int pp = w - 4;          // staging pair id for waves 4-7
  int q1a = 0, r1a = 0, q1b = 0, r1b = 0;
  if (w >= 4) {
    int qa = qb[2 * pp],     ra = rb[2 * pp];
    int qc = qb[2 * pp + 1], rc = rb[2 * pp + 1];
    float2 ea = *(const float2*)(ead_tab + (qa * KK + ra) * 128 + 2 * v);
    float2 eb = *(const float2*)(ead_tab + (qc * KK + rc) * 128 + 2 * v);
    eadbuf[0][pp][v] = (v4f){ea.x, ea.y, eb.x, eb.y};
    q1a = qb[8 + 2 * pp];     r1a = rb[8 + 2 * pp];
    q1b = qb[8 + 2 * pp + 1]; r1b = rb[8 + 2 * pp + 1];
  }

  v2f vm0, vm1, vm2, vm3;
  {
    int m = mbase;
    vm0.x = init_vm[(m + 0) * VD + v]; vm0.y = init_vm[(m + 1) * VD + v];
    vm1.x = init_vm[(m + 2) * VD + v]; vm1.y = init_vm[(m + 3) * VD + v];
    if (m + 4 < MM) { vm2.x = init_vm[(m + 4) * VD + v]; vm2.y = init_vm[(m + 5) * VD + v]; }
    else vm2 = (v2f)(0.f);
    if (m + 6 < MM) { vm3.x = init_vm[(m + 6) * VD + v]; vm3.y = init_vm[(m + 7) * VD + v]; }
    else vm3 = (v2f)(0.f);
  }
  __syncthreads();   // sidx_a + eadbuf[0] visible

  // ---- load window-0 a-slices into SGPR buffer (8 x s_load_dwordx8) ----
  f32x8 arow[8];
  {
    int4 p0 = *(const int4*)&sidx_a[0];
    int4 p1 = *(const int4*)&sidx_a[4];
    uint32_t o0 = RL(p0.x + wb), o1 = RL(p0.y + wb);
    uint32_t o2 = RL(p0.z + wb), o3 = RL(p0.w + wb);
    uint32_t o4 = RL(p1.x + wb), o5 = RL(p1.y + wb);
    uint32_t o6 = RL(p1.z + wb), o7 = RL(p1.w + wb);
    SLOAD(arow[0], o0); SLOAD(arow[1], o1); SLOAD(arow[2], o2); SLOAD(arow[3], o3);
    SLOAD(arow[4], o4); SLOAD(arow[5], o5); SLOAD(arow[6], o6); SLOAD(arow[7], o7);
  }
  LGKM_BARRIER();
  SCHED_FENCE();

  v4f edp[2];

  // one step of the recurrence, a from SGPRs, (e,ad) scalar pair
#define HALFSTEP(kk_, e_, ad_, accv_) {                              \
    v2f e2 = {e_, e_}, ad2 = {ad_, ad_};                             \
    v2f aL0 = {arow[kk_][0], arow[kk_][1]};                          \
    v2f aL1 = {arow[kk_][2], arow[kk_][3]};                          \
    v2f aH0 = {arow[kk_][4], arow[kk_][5]};                          \
    v2f aH1 = {arow[kk_][6], arow[kk_][7]};                          \
    v2f acc;                                                         \
    acc  = aL0 * vm0;  vm0 += aL0 * (ad2 - e2 * vm0);                \
    acc += aL1 * vm1;  vm1 += aL1 * (ad2 - e2 * vm1);                \
    acc += aH0 * vm2;  vm2 += aH0 * (ad2 - e2 * vm2);                \
    acc += aH1 * vm3;  vm3 += aH1 * (ad2 - e2 * vm3);                \
    accv_ = acc.x + acc.y;                                           \
  }

  // PAIR p: steps 2p,2p+1; consumes edp ring; reloads arow slots for next window
#define PAIR(buf_, p_) {                                             \
    v4f ed = edp[(p_) & 1];                                          \
    if ((p_) < 2) edp[(p_) & 1] = eadbuf[buf_][(p_) + 2][v];         \
    float accA, accB;                                                \
    HALFSTEP(2 * (p_), ed.x, ed.y, accA)                             \
    SLOAD(arow[2 * (p_)], onext##p_##a);                             \
    HALFSTEP(2 * (p_) + 1, ed.z, ed.w, accB)                         \
    SLOAD(arow[2 * (p_) + 1], onext##p_##b);                         \
    red2[buf_][p_][w][v] = (v2f){accA, accB};                        \
  }

  for (int wi = 0; wi < NWIN; ++wi) {
    const int buf = wi & 1;
    const int nb = buf ^ 1;

    // next-window a byte offsets (uniform b128 reads + readfirstlane)
    int4 p0 = *(const int4*)&sidx_a[(wi + 1) * 8];
    int4 p1 = *(const int4*)&sidx_a[(wi + 1) * 8 + 4];
    uint32_t onext0a = RL(p0.x + wb), onext0b = RL(p0.y + wb);
    uint32_t onext1a = RL(p0.z + wb), onext1b = RL(p0.w + wb);
    uint32_t onext2a = RL(p1.x + wb), onext2b = RL(p1.y + wb);
    uint32_t onext3a = RL(p1.z + wb), onext3b = RL(p1.w + wb);

    // edp preload for pairs 0,1
    edp[0] = eadbuf[buf][0][v];
    edp[1] = eadbuf[buf][1][v];

    // role-split window work:
    float2 ea_st, eb_st;
    if (w >= 4) {
      // staging waves: gather window wi+1's ead pair (VMEM, consumed post-STEPs)
      ea_st = *(const float2*)(ead_tab + (q1a * KK + r1a) * 128 + 2 * v);
      eb_st = *(const float2*)(ead_tab + (q1b * KK + r1b) * 128 + 2 * v);
      // prefetch q/r for window wi+2
      int i2 = (wi + 2) * 8 + 2 * pp;
      int i2a = (i2 < SS) ? i2 : (SS - 1);
      int i2b = (i2 + 1 < SS) ? (i2 + 1) : (SS - 1);
      q1a = qb[i2a]; r1a = rb[i2a];
      q1b = qb[i2b]; r1b = rb[i2b];
    } else if (wi > 0) {
      // flush waves: pair w of window wi-1 -> rows (wi-1)*8 + 2w, +1
      v2f s = (v2f)(0.f);
#pragma unroll
      for (int wv = 0; wv < NW; ++wv) s += red2[nb][w][wv][v];
      size_t rowb = (size_t)((wi - 1) * WIN + 2 * w) * 64 + v;
      outp[rowb] = s.x;
      outp[rowb + 64] = s.y;
    }

    // compute 4 pairs (8 steps)
    PAIR(buf, 0) PAIR(buf, 1) PAIR(buf, 2) PAIR(buf, 3)

    // staging write (waves 4-7)
    if (w >= 4) eadbuf[nb][pp][v] = (v4f){ea_st.x, ea_st.y, eb_st.x, eb_st.y};

    LGKM_BARRIER();   // drains LDS ops + this window's s_loads
    SCHED_FENCE();
  }

  // ---- tail: window 62 = steps 496..499 (pairs 0,1), buf 0 ----
  {
    uint32_t onext0a, onext0b, onext1a, onext1b;
    {
      int4 p0 = *(const int4*)&sidx_a[504];   // clamped entries, harmless reloads
      onext0a = RL(p0.x + wb); onext0b = RL(p0.y + wb);
      onext1a = RL(p0.z + wb); onext1b = RL(p0.w + wb);
    }
    edp[0] = eadbuf[0][0][v];
    edp[1] = eadbuf[0][1][v];
    if (w < 4) {                 // flush window 61 (red2[1])
      v2f s = (v2f)(0.f);
#pragma unroll
      for (int wv = 0; wv < NW; ++wv) s += red2[1][w][wv][v];
      size_t rowb = (size_t)((NWIN - 1) * WIN + 2 * w) * 64 + v;
      outp[rowb] = s.x;
      outp[rowb + 64] = s.y;
    }
    PAIR(0, 0) PAIR(0, 1)
    LGKM_BARRIER();
    SCHED_FENCE();
    if (w < 2) {                 // final flush: rows 496..499
      v2f s = (v2f)(0.f);
#pragma unroll
      for (int wv = 0; wv < NW; ++wv) s += red2[0][w][wv][v];
      size_t rowb = (size_t)(NWIN * WIN + 2 * w) * 64 + v;
      outp[rowb] = s.x;
      outp[rowb + 64] = s.y;
    }
  }
#undef PAIR
#undef HALFSTEP
}

// ---------------- kernel 3: summary + logits + softmax ----------------
__global__ __launch_bounds__(64) void k_out(
    const float* __restrict__ reads, const int* __restrict__ qs,
    const float* __restrict__ sq_tab, const float* __restrict__ WsT,
    const float* __restrict__ bs, const float* __restrict__ WcT,
    const float* __restrict__ bc,
    float* __restrict__ out_logits, float* __restrict__ out_probs) {
  __shared__ float xs[64 * 65];
  const int lane = threadIdx.x;
  const long rowbase = (long)blockIdx.x * 64;
  const float* __restrict__ src = reads + rowbase * 64;

#pragma unroll 8
  for (int it = 0; it < 64; ++it)
    xs[it * 65 + lane] = src[it * 64 + lane];
  __syncthreads();

  float x[64];
#pragma unroll
  for (int i = 0; i < 64; ++i) x[i] = xs[lane * 65 + i];

  const long row = rowbase + lane;
  const int q = qs[row];
  const float* __restrict__ sqrow = sq_tab + (long)q * 64;

  float sm[SD];
#pragma unroll
  for (int j = 0; j < SD; ++j) {
    float acc = bs[j] + sqrow[j];
    const float* __restrict__ wrow = WsT + j * 64;  // uniform -> s_load
#pragma unroll
    for (int i = 0; i < 64; ++i) acc = fmaf(x[i], wrow[i], acc);
    float ex = __expf(2.f * acc);
    sm[j] = (ex - 1.f) / (ex + 1.f);
  }

  float lg[KK];
#pragma unroll
  for (int c = 0; c < KK; ++c) {
    float acc = bc[c];
    const float* __restrict__ wrow = WcT + c * SD;  // uniform -> s_load
#pragma unroll
    for (int j = 0; j < SD; ++j) acc = fmaf(sm[j], wrow[j], acc);
    lg[c] = acc;
  }

  float mx = lg[0];
#pragma unroll
  for (int c = 1; c < KK; ++c) mx = fmaxf(mx, lg[c]);
  float p[KK], sum = 0.f;
#pragma unroll
  for (int c = 0; c < KK; ++c) { p[c] = __expf(lg[c] - mx); sum += p[c]; }
  float inv = 1.f / sum;
#pragma unroll
  for (int c = 0; c < KK; ++c) {
    out_logits[row * KK + c] = lg[c];
    out_probs[row * KK + c] = p[c] * inv;
  }
}

extern "C" void kernel_launch(void* const* d_in, const int* in_sizes, int n_in,
                              void* d_out, int out_size, void* d_ws, size_t ws_size,
                              hipStream_t stream) {
  const int*   questions  = (const int*)  d_in[0];
  const int*   responses  = (const int*)  d_in[1];
  const float* q_table    = (const float*)d_in[2];
  const float* item_table = (const float*)d_in[3];
  const float* Wv         = (const float*)d_in[4];
  const float* bv         = (const float*)d_in[5];
  const float* key_mem    = (const float*)d_in[6];
  const float* init_vm    = (const float*)d_in[7];
  const float* We         = (const float*)d_in[8];
  const float* be         = (const float*)d_in[9];
  const float* Wa         = (const float*)d_in[10];
  const float* ba         = (const float*)d_in[11];
  const float* Ws         = (const float*)d_in[12];
  const float* bs         = (const float*)d_in[13];
  const float* Wc         = (const float*)d_in[14];
  const float* bc         = (const float*)d_in[15];

  float* ws       = (float*)d_ws;
  float* attn_tab = ws + OFF_ATTN;
  float* sq_tab   = ws + OFF_SQ;
  float* ead_tab  = ws + OFF_EAD;
  float* WsT      = ws + OFF_WST;
  float* WcT      = ws + OFF_WCT;
  float* reads    = ws + OFF_READS;

  float* out_logits = (float*)d_out;
  float* out_probs  = out_logits + (size_t)BB * SS * KK;

  hipLaunchKernelGGL(k_tabs, dim3(NQ1 + 1 + NQ1 * KK), dim3(64), 0, stream,
                     q_table, item_table, key_mem, Wv, bv, We, be, Wa, ba, Ws, Wc,
                     attn_tab, sq_tab, ead_tab, WsT, WcT);
  hipLaunchKernelGGL(k_scan, dim3(BB), dim3(NW * 64), 0, stream,
                     questions, responses, attn_tab, ead_tab, init_vm, reads);
  hipLaunchKernelGGL(k_out, dim3(BB * SS / 64), dim3(64), 0, stream,
                     reads, questions, sq_tab, WsT, bs, WcT, bc,
                     out_logits, out_probs);
}